// Round 7
// baseline (942.383 us; speedup 1.0000x reference)
//
#include <hip/hip_runtime.h>
#include <hip/hip_bf16.h>

// Problem constants (cheb_conv): B=16, N=50000, FIN=32, FOUT=32, K=6, NNZ=800000
#define NND   50000
#define NBATCH 16
#define NFIN  32
#define NFOUT 32
#define NCHEB 6
#define NNZE  800000
#define DDIM  512   // NBATCH*NFIN
#define NSLICE 8    // feature slices; slice s -> XCD via blockIdx&7 (perf heuristic only)

typedef __attribute__((ext_vector_type(8))) short    short8;
typedef __attribute__((ext_vector_type(4))) short    short4v;
typedef __attribute__((ext_vector_type(8))) unsigned short u16x8;
typedef __attribute__((ext_vector_type(4))) float    f32x4;
typedef __attribute__((ext_vector_type(2))) float    f32x2;

__device__ __forceinline__ float b2f(unsigned short u) {
  union { unsigned u; float f; } v; v.u = ((unsigned)u) << 16; return v.f;
}
__device__ __forceinline__ unsigned short f2bf(float f) {
  union { float f; unsigned u; } v; v.f = f;
  unsigned r = v.u + 0x7fffu + ((v.u >> 16) & 1u);   // RNE
  return (unsigned short)(r >> 16);
}
// f32 -> OCP e4m3fn byte, software RNE
__device__ __forceinline__ unsigned f2fp8(float f) {
  unsigned s = (__float_as_uint(f) >> 24) & 0x80u;
  float af = fminf(fabsf(f), 448.0f);
  unsigned b;
  if (af < 0.015625f) {
    b = (unsigned)__float2int_rn(af * 512.0f);
  } else {
    unsigned u = __float_as_uint(af);
    u += 0x7FFFFu + ((u >> 20) & 1u);
    b = (((u >> 23) - 120u) << 3) | ((u >> 20) & 7u);
    if (b > 0x7Eu) b = 0x7Eu;
  }
  return s | b;
}

// ---------------- CSR build ----------------
__global__ void hist_kernel(const int* __restrict__ rows, int* __restrict__ cnt, int nnz) {
  int e = blockIdx.x * blockDim.x + threadIdx.x;
  if (e < nnz) atomicAdd(&cnt[rows[e]], 1);
}

__global__ __launch_bounds__(1024) void scanA_kernel(const int* __restrict__ cnt,
                                                     int* __restrict__ rowptr,
                                                     int* __restrict__ partials, int n) {
  __shared__ int lds[1024];
  int b = blockIdx.x, tid = threadIdx.x, i = b * 1024 + tid;
  int v = (i < n) ? cnt[i] : 0;
  lds[tid] = v;
  __syncthreads();
  int s = v;
  for (int off = 1; off < 1024; off <<= 1) {
    int t = (tid >= off) ? lds[tid - off] : 0;
    __syncthreads();
    s += t;
    lds[tid] = s;
    __syncthreads();
  }
  if (i < n) rowptr[i] = s - v;
  if (tid == 1023) partials[b] = s;
}

// merged: thread 0 = serial partial-scan; threads 64..831 = W -> MFMA B-frag pack
__global__ void scanB_wprep(int* __restrict__ partials, int nb,
                            const float* __restrict__ W, unsigned short* __restrict__ Wfrag) {
  int t = threadIdx.x;
  if (t == 0) {
    int run = 0;
    for (int b = 0; b < nb; ++b) { int x = partials[b]; partials[b] = run; run += x; }
  } else if (t >= 64 && t < 64 + 768) {
    int w = t - 64;
    int frag = w >> 6, lane = w & 63;
    int kk = frag >> 1, h = frag & 1;
    int fo = (lane & 15) + h * 16, kc = (lane >> 4) * 8;
    u16x8 b;
#pragma unroll
    for (int j = 0; j < 8; ++j)
      b[j] = f2bf(W[((size_t)(kc + j) * NCHEB + kk) * NFOUT + fo]);
    *(u16x8*)(Wfrag + (size_t)w * 8) = b;
  }
}

__global__ __launch_bounds__(1024) void scanC_kernel(const int* __restrict__ partials,
                                                     int* __restrict__ rowptr,
                                                     int* __restrict__ cursor, int n) {
  int i = blockIdx.x * 1024 + threadIdx.x;
  if (i < n) {
    int r = rowptr[i] + partials[blockIdx.x];
    rowptr[i] = r;
    cursor[i] = r;
  }
  if (i == n) rowptr[n] = NNZE;
}

// packed edges: ecv[p] = (col in low 32) | (val bits in high 32)
__global__ void fill_kernel(const int* __restrict__ rows, const int* __restrict__ cols,
                            const float* __restrict__ vals, int* __restrict__ cursor,
                            long* __restrict__ ecv, int nnz) {
  int e = blockIdx.x * blockDim.x + threadIdx.x;
  if (e < nnz) {
    int r = rows[e];
    int p = atomicAdd(&cursor[r], 1);
    ecv[p] = (long)((unsigned long long)__float_as_uint(vals[e]) << 32 | (unsigned)cols[e]);
  }
}

// ---------------- slice-major layout ----------------
// T element (s, n, pos): index ((s*NND)+n)*64 + pos, pos = (fi - 4s) + 4*b.
// bf16 arrays indexed in elements, fp8 arrays in bytes: SAME index expression.
// Slice row = 64 B (fp8) = exactly one cache line per edge per slice.

// ---------------- Level 0: x -> T0 (bf16 slice-major into Tall) + fp8 copy ----------------
__global__ __launch_bounds__(256) void cheb_k0_slice(const float* __restrict__ x,
                                                     unsigned short* __restrict__ Tb0,
                                                     char* __restrict__ Tq0) {
  int wave = threadIdx.x >> 6, lane = threadIdx.x & 63;
  int n = blockIdx.x * 4 + wave;
  int bb = lane & 15, kc = (lane >> 4) * 8;
  int sA = kc >> 2;                       // fi kc..kc+3 -> slice sA; kc+4..kc+7 -> sA+1

  const float* xp = x + ((size_t)bb * NND + n) * NFIN + kc;
  float4 xa = *(const float4*)xp;
  float4 xb = *(const float4*)(xp + 4);
  float tv[8] = {xa.x, xa.y, xa.z, xa.w, xb.x, xb.y, xb.z, xb.w};

  size_t roA = ((size_t)sA * NND + n) * 64 + 4 * bb;
  size_t roB = roA + (size_t)NND * 64;

  short4v lo, hi;
#pragma unroll
  for (int j = 0; j < 4; ++j) { lo[j] = (short)f2bf(tv[j]); hi[j] = (short)f2bf(tv[4 + j]); }
  *(short4v*)(Tb0 + roA) = lo;
  *(short4v*)(Tb0 + roB) = hi;

  unsigned qlo = f2fp8(tv[0]) | (f2fp8(tv[1]) << 8) | (f2fp8(tv[2]) << 16) | (f2fp8(tv[3]) << 24);
  unsigned qhi = f2fp8(tv[4]) | (f2fp8(tv[5]) << 8) | (f2fp8(tv[6]) << 16) | (f2fp8(tv[7]) << 24);
  *(int*)(Tq0 + roA) = (int)qlo;
  *(int*)(Tq0 + roB) = (int)qhi;
}

// ---------------- Sliced levels 1..4: gather L2-local, T_{k-2} bf16, dst bf16+fp8 --------
// blockIdx&7 = slice (XCD pin heuristic); wave = 4 nodes x 16 lanes (one dword/lane).
__global__ __launch_bounds__(256) void cheb_level_slice(const char* __restrict__ Tqprev,
                                                        const unsigned short* __restrict__ TppB,
                                                        unsigned short* __restrict__ TdstB,
                                                        char* __restrict__ TdstQ,
                                                        const int* __restrict__ rowptr,
                                                        const long* __restrict__ ecv,
                                                        float alpha, float beta) {
  int s    = blockIdx.x & 7;
  int blk  = blockIdx.x >> 3;
  int wave = threadIdx.x >> 6, lane = threadIdx.x & 63;
  int g = lane >> 4, fl = lane & 15;
  int n = blk * 16 + wave * 4 + g;

  int s0 = rowptr[n], deg = rowptr[n + 1] - s0;
  const char* qsrc = Tqprev + (size_t)s * ((size_t)NND * 64) + 4 * fl;

  float acc[4] = {0.f, 0.f, 0.f, 0.f};
  for (int i = 0; i < deg; i += 8) {          // padded 8-batch; pad val=0 (exact no-op)
    int cols[8]; float vals[8];
#pragma unroll
    for (int q = 0; q < 8; ++q) {
      int idx = (i + q < deg) ? (i + q) : (deg - 1);
      long m = __builtin_nontemporal_load(ecv + s0 + idx);
      cols[q] = (int)(unsigned)m;
      vals[q] = (i + q < deg) ? __int_as_float((int)(m >> 32)) : 0.f;
    }
    int d[8];
#pragma unroll
    for (int q = 0; q < 8; ++q) d[q] = *(const int*)(qsrc + (size_t)cols[q] * 64);
#pragma unroll
    for (int q = 0; q < 8; ++q) {
      f32x2 f01 = __builtin_amdgcn_cvt_pk_f32_fp8(d[q], false);
      f32x2 f23 = __builtin_amdgcn_cvt_pk_f32_fp8(d[q], true);
      acc[0] = fmaf(vals[q], f01.x, acc[0]);
      acc[1] = fmaf(vals[q], f01.y, acc[1]);
      acc[2] = fmaf(vals[q], f23.x, acc[2]);
      acc[3] = fmaf(vals[q], f23.y, acc[3]);
    }
  }

  size_t ro = ((size_t)s * NND + n) * 64 + 4 * fl;
  float tk[4];
  if (beta != 0.f) {
    short4v tb = *(const short4v*)(TppB + ro);   // T_{k-2} ALWAYS bf16 (R4 numerics)
#pragma unroll
    for (int j = 0; j < 4; ++j) tk[j] = alpha * acc[j] - beta * b2f((unsigned short)tb[j]);
  } else {
#pragma unroll
    for (int j = 0; j < 4; ++j) tk[j] = alpha * acc[j];
  }

  short4v o;
#pragma unroll
  for (int j = 0; j < 4; ++j) o[j] = (short)f2bf(tk[j]);
  __builtin_nontemporal_store(o, (short4v*)(TdstB + ro));   // stream; epilogue reads later

  unsigned w = f2fp8(tk[0]) | (f2fp8(tk[1]) << 8) | (f2fp8(tk[2]) << 16) | (f2fp8(tk[3]) << 24);
  *(int*)(TdstQ + ro) = (int)w;                 // next level gathers this (L2-retain)
}

// ---------------- Level 5 fused with epilogue (R4 numerics, slice-major addressing) ------
// Gather Tq4 as 2 dwords/lane/edge (slices sA, sA+1) = same 8 lines/edge as R4.
__global__ __launch_bounds__(256) void cheb_l5_epi_slice(const char* __restrict__ Tq4,
                                                         const unsigned short* __restrict__ Tall,
                                                         const unsigned short* __restrict__ Wfrag,
                                                         const int* __restrict__ rowptr,
                                                         const long* __restrict__ ecv,
                                                         float* __restrict__ out) {
  int wave = threadIdx.x >> 6, lane = threadIdx.x & 63;
  int n = blockIdx.x * 4 + wave;
  int bb = lane & 15, kc = (lane >> 4) * 8;
  int sA = kc >> 2;
  size_t roA = ((size_t)sA * NND + n) * 64 + 4 * bb;
  size_t roB = roA + (size_t)NND * 64;

  int s0 = rowptr[n], e1 = rowptr[n + 1];
  const char* qlo = Tq4 + (size_t)sA * ((size_t)NND * 64) + 4 * bb;
  const char* qhi = qlo + (size_t)NND * 64;

  float acc[8] = {0.f, 0.f, 0.f, 0.f, 0.f, 0.f, 0.f, 0.f};
  int e = s0;
  for (; e + 8 <= e1; e += 8) {
    long m[8];
#pragma unroll
    for (int q = 0; q < 8; ++q) m[q] = __builtin_nontemporal_load(ecv + e + q);
    int dlo[8], dhi[8];
#pragma unroll
    for (int q = 0; q < 8; ++q) {
      size_t co = (size_t)(unsigned)m[q] * 64;
      dlo[q] = *(const int*)(qlo + co);
      dhi[q] = *(const int*)(qhi + co);
    }
#pragma unroll
    for (int q = 0; q < 8; ++q) {
      float v = __int_as_float((int)(m[q] >> 32));
      f32x2 f01 = __builtin_amdgcn_cvt_pk_f32_fp8(dlo[q], false);
      f32x2 f23 = __builtin_amdgcn_cvt_pk_f32_fp8(dlo[q], true);
      f32x2 f45 = __builtin_amdgcn_cvt_pk_f32_fp8(dhi[q], false);
      f32x2 f67 = __builtin_amdgcn_cvt_pk_f32_fp8(dhi[q], true);
      acc[0] = fmaf(v, f01.x, acc[0]);
      acc[1] = fmaf(v, f01.y, acc[1]);
      acc[2] = fmaf(v, f23.x, acc[2]);
      acc[3] = fmaf(v, f23.y, acc[3]);
      acc[4] = fmaf(v, f45.x, acc[4]);
      acc[5] = fmaf(v, f45.y, acc[5]);
      acc[6] = fmaf(v, f67.x, acc[6]);
      acc[7] = fmaf(v, f67.y, acc[7]);
    }
  }
  for (; e < e1; ++e) {
    long mm = __builtin_nontemporal_load(ecv + e);
    size_t co = (size_t)(unsigned)mm * 64;
    int dl = *(const int*)(qlo + co);
    int dh = *(const int*)(qhi + co);
    float v = __int_as_float((int)(mm >> 32));
    f32x2 f01 = __builtin_amdgcn_cvt_pk_f32_fp8(dl, false);
    f32x2 f23 = __builtin_amdgcn_cvt_pk_f32_fp8(dl, true);
    f32x2 f45 = __builtin_amdgcn_cvt_pk_f32_fp8(dh, false);
    f32x2 f67 = __builtin_amdgcn_cvt_pk_f32_fp8(dh, true);
    acc[0] = fmaf(v, f01.x, acc[0]);
    acc[1] = fmaf(v, f01.y, acc[1]);
    acc[2] = fmaf(v, f23.x, acc[2]);
    acc[3] = fmaf(v, f23.y, acc[3]);
    acc[4] = fmaf(v, f45.x, acc[4]);
    acc[5] = fmaf(v, f45.y, acc[5]);
    acc[6] = fmaf(v, f67.x, acc[6]);
    acc[7] = fmaf(v, f67.y, acc[7]);
  }

  short8 a[6];
#pragma unroll
  for (int kk = 0; kk < 5; ++kk) {
    short4v lo = *(const short4v*)(Tall + (size_t)kk * NND * DDIM + roA);
    short4v hi = *(const short4v*)(Tall + (size_t)kk * NND * DDIM + roB);
    short8 r;
    r[0]=lo[0]; r[1]=lo[1]; r[2]=lo[2]; r[3]=lo[3];
    r[4]=hi[0]; r[5]=hi[1]; r[6]=hi[2]; r[7]=hi[3];
    a[kk] = r;
  }

  u16x8 tp2 = __builtin_bit_cast(u16x8, a[3]);   // T3 (bf16) doubles as T_{k-2}
  u16x8 t5b;
#pragma unroll
  for (int j = 0; j < 8; ++j) t5b[j] = f2bf(2.f * acc[j] - b2f(tp2[j]));
  a[5] = __builtin_bit_cast(short8, t5b);

  int fo = lane & 15;
  f32x4 c0 = {0.f, 0.f, 0.f, 0.f}, c1 = {0.f, 0.f, 0.f, 0.f};
#pragma unroll
  for (int kk = 0; kk < 6; ++kk) {
    short8 B0 = *(const short8*)(Wfrag + ((size_t)(kk * 2 + 0) * 64 + lane) * 8);
    short8 B1 = *(const short8*)(Wfrag + ((size_t)(kk * 2 + 1) * 64 + lane) * 8);
    c0 = __builtin_amdgcn_mfma_f32_16x16x32_bf16(a[kk], B0, c0, 0, 0, 0);
    c1 = __builtin_amdgcn_mfma_f32_16x16x32_bf16(a[kk], B1, c1, 0, 0, 0);
  }

  int br = (lane >> 4) * 4;
#pragma unroll
  for (int r = 0; r < 4; ++r) {
    size_t o = ((size_t)(br + r) * NND + n) * NFOUT + fo;
    out[o]      = c0[r];
    out[o + 16] = c1[r];
  }
}

// ================= Fallback (bf16 fused epilogue, 2-buffer ping-pong) =================
__device__ __forceinline__ void gather_row(const unsigned short* __restrict__ gbase,
                                           const int* __restrict__ ccol,
                                           const float* __restrict__ cval,
                                           int s, int e1, float acc[8]) {
  int e = s;
  for (; e + 4 <= e1; e += 4) {
    int c[4]; float v[4];
#pragma unroll
    for (int q = 0; q < 4; ++q) {
      c[q] = __builtin_nontemporal_load(ccol + e + q);
      v[q] = __builtin_nontemporal_load(cval + e + q);
    }
    u16x8 t[4];
#pragma unroll
    for (int q = 0; q < 4; ++q) t[q] = *(const u16x8*)(gbase + (size_t)c[q] * DDIM);
#pragma unroll
    for (int q = 0; q < 4; ++q)
#pragma unroll
      for (int j = 0; j < 8; ++j) acc[j] = fmaf(v[q], b2f(t[q][j]), acc[j]);
  }
  for (; e < e1; ++e) {
    int   ci = __builtin_nontemporal_load(ccol + e);
    float vi = __builtin_nontemporal_load(cval + e);
    u16x8 ti = *(const u16x8*)(gbase + (size_t)ci * DDIM);
#pragma unroll
    for (int j = 0; j < 8; ++j) acc[j] = fmaf(vi, b2f(ti[j]), acc[j]);
  }
}

__global__ void scan_kernel(const int* __restrict__ cnt, int* __restrict__ rowptr,
                            int* __restrict__ cursor, int n) {
  __shared__ int lds[1024];
  int tid = threadIdx.x;
  int run = 0;
  for (int base = 0; base <= n; base += 1024) {
    int i = base + tid;
    int v = (i < n) ? cnt[i] : 0;
    lds[tid] = v;
    __syncthreads();
    int s = v;
    for (int off = 1; off < 1024; off <<= 1) {
      int t = (tid >= off) ? lds[tid - off] : 0;
      __syncthreads();
      s += t;
      lds[tid] = s;
      __syncthreads();
    }
    int excl = run + s - v;
    if (i <= n) {
      rowptr[i] = excl;
      if (i < n) cursor[i] = excl;
    }
    run += lds[1023];
    __syncthreads();
  }
}

__global__ void fill2_kernel(const int* __restrict__ rows, const int* __restrict__ cols,
                             const float* __restrict__ vals, int* __restrict__ cursor,
                             int* __restrict__ ccol, float* __restrict__ cval, int nnz) {
  int e = blockIdx.x * blockDim.x + threadIdx.x;
  if (e < nnz) {
    int r = rows[e];
    int p = atomicAdd(&cursor[r], 1);
    ccol[p] = cols[e];
    cval[p] = vals[e];
  }
}

__global__ __launch_bounds__(256) void cheb_k0_fused(const float* __restrict__ x,
                                                     unsigned short* __restrict__ T0,
                                                     const float* __restrict__ W,
                                                     float* __restrict__ out) {
  int wave = threadIdx.x >> 6, lane = threadIdx.x & 63;
  int n = blockIdx.x * 4 + wave;
  int fo = lane & 15, kc = (lane >> 4) * 8;
  int b  = lane & 15;

  const float* xp = x + ((size_t)b * NND + n) * NFIN + kc;
  float4 xa = *(const float4*)xp;
  float4 xb = *(const float4*)(xp + 4);
  float tv[8] = {xa.x, xa.y, xa.z, xa.w, xb.x, xb.y, xb.z, xb.w};

  u16x8 tb;
#pragma unroll
  for (int j = 0; j < 8; ++j) tb[j] = f2bf(tv[j]);
  *(u16x8*)(T0 + (size_t)n * DDIM + lane * 8) = tb;

  short8 B0, B1;
#pragma unroll
  for (int j = 0; j < 8; ++j) {
    int fi = kc + j;
    const float* wp = W + ((size_t)fi * NCHEB + 0) * NFOUT + fo;
    B0[j] = (short)f2bf(wp[0]);
    B1[j] = (short)f2bf(wp[16]);
  }
  f32x4 c0 = {0.f, 0.f, 0.f, 0.f}, c1 = {0.f, 0.f, 0.f, 0.f};
  short8 a = __builtin_bit_cast(short8, tb);
  c0 = __builtin_amdgcn_mfma_f32_16x16x32_bf16(a, B0, c0, 0, 0, 0);
  c1 = __builtin_amdgcn_mfma_f32_16x16x32_bf16(a, B1, c1, 0, 0, 0);

  int br = (lane >> 4) * 4;
#pragma unroll
  for (int r = 0; r < 4; ++r) {
    size_t o = ((size_t)(br + r) * NND + n) * NFOUT + fo;
    out[o]      = c0[r];
    out[o + 16] = c1[r];
  }
}

__global__ __launch_bounds__(256) void cheb_level_fused(const unsigned short* __restrict__ Tprev,
                                                        unsigned short* __restrict__ Tio,
                                                        const int* __restrict__ rowptr,
                                                        const int* __restrict__ ccol,
                                                        const float* __restrict__ cval,
                                                        const float* __restrict__ W,
                                                        float* __restrict__ out,
                                                        int kk, float alpha, float beta, int writeT) {
  int wave = threadIdx.x >> 6, lane = threadIdx.x & 63;
  int n = blockIdx.x * 4 + wave;
  int fo = lane & 15, kc = (lane >> 4) * 8;

  short8 B0, B1;
#pragma unroll
  for (int j = 0; j < 8; ++j) {
    int fi = kc + j;
    const float* wp = W + ((size_t)fi * NCHEB + kk) * NFOUT + fo;
    B0[j] = (short)f2bf(wp[0]);
    B1[j] = (short)f2bf(wp[16]);
  }

  float acc[8] = {0.f, 0.f, 0.f, 0.f, 0.f, 0.f, 0.f, 0.f};
  int s = rowptr[n], e1 = rowptr[n + 1];
  gather_row(Tprev + lane * 8, ccol, cval, s, e1, acc);

  unsigned short* iop = Tio + (size_t)n * DDIM + lane * 8;
  float tk[8];
  if (beta != 0.f) {
    u16x8 tp2 = *(const u16x8*)iop;
#pragma unroll
    for (int j = 0; j < 8; ++j) tk[j] = alpha * acc[j] - beta * b2f(tp2[j]);
  } else {
#pragma unroll
    for (int j = 0; j < 8; ++j) tk[j] = alpha * acc[j];
  }

  u16x8 tkb;
#pragma unroll
  for (int j = 0; j < 8; ++j) tkb[j] = f2bf(tk[j]);
  if (writeT) *(u16x8*)iop = tkb;

  f32x4 c0 = {0.f, 0.f, 0.f, 0.f}, c1 = {0.f, 0.f, 0.f, 0.f};
  short8 a = __builtin_bit_cast(short8, tkb);
  c0 = __builtin_amdgcn_mfma_f32_16x16x32_bf16(a, B0, c0, 0, 0, 0);
  c1 = __builtin_amdgcn_mfma_f32_16x16x32_bf16(a, B1, c1, 0, 0, 0);

  int br = (lane >> 4) * 4;
#pragma unroll
  for (int r = 0; r < 4; ++r) {
    size_t o = ((size_t)(br + r) * NND + n) * NFOUT + fo;
    out[o]      += c0[r];
    out[o + 16] += c1[r];
  }
}

// ---------------- launch ----------------
static inline size_t alignup(size_t v) { return (v + 255) & ~(size_t)255; }

extern "C" void kernel_launch(void* const* d_in, const int* in_sizes, int n_in,
                              void* d_out, int out_size, void* d_ws, size_t ws_size,
                              hipStream_t stream) {
  const float* x    = (const float*)d_in[0];
  const int*   rows = (const int*)d_in[1];
  const int*   cols = (const int*)d_in[2];
  const float* vals = (const float*)d_in[3];
  const float* W    = (const float*)d_in[4];
  float* out = (float*)d_out;

  const size_t tbytes = alignup((size_t)NND * DDIM * 2);     // one bf16 T level (51.2 MB)
  const size_t qbytes = alignup((size_t)NND * 512);          // one fp8 T level (25.6 MB)
  const size_t small  = alignup((size_t)(NND + 1) * 4);
  const size_t need_s = 5 * tbytes + 2 * qbytes + alignup(12 * 64 * 8 * 2)
                      + 4 * small + alignup((size_t)NNZE * 8);   // ~314 MB (= R4 proven)

  const int grid  = NND / 4;                 // 12500 blocks, one wave per node
  const int sgrid = (NND / 16) * NSLICE;     // 3125 node-blocks x 8 slices = 25000
  const int nscan = (NND + 1023) / 1024;     // 49

  if (ws_size >= need_s) {
    // ---------- L2-sliced fp8-gather path, R4 numerics ----------
    char* p = (char*)d_ws;
    size_t off = 0;
    unsigned short* Tall = (unsigned short*)(p + off); off += 5 * tbytes;  // T0..T4 bf16 slice-major
    char* TqA = (char*)(p + off); off += qbytes;
    char* TqB = (char*)(p + off); off += qbytes;
    unsigned short* Wfrag = (unsigned short*)(p + off); off += alignup(12 * 64 * 8 * 2);
    int*  cnt      = (int*)(p + off); off += small;
    int*  rowptr   = (int*)(p + off); off += small;
    int*  cursor   = (int*)(p + off); off += small;
    int*  partials = (int*)(p + off); off += small;
    long* ecv      = (long*)(p + off); off += alignup((size_t)NNZE * 8);

    hipMemsetAsync(cnt, 0, (size_t)NND * 4, stream);
    hist_kernel<<<(NNZE + 255) / 256, 256, 0, stream>>>(rows, cnt, NNZE);
    scanA_kernel<<<nscan, 1024, 0, stream>>>(cnt, rowptr, partials, NND);
    scanB_wprep<<<1, 832, 0, stream>>>(partials, nscan, W, Wfrag);
    scanC_kernel<<<nscan, 1024, 0, stream>>>(partials, rowptr, cursor, NND);
    fill_kernel<<<(NNZE + 255) / 256, 256, 0, stream>>>(rows, cols, vals, cursor, ecv, NNZE);

    auto Tk = [&](int k) { return Tall + (size_t)k * NND * DDIM; };

    cheb_k0_slice<<<grid, 256, 0, stream>>>(x, Tk(0), TqA);
    // T1 = L T0
    cheb_level_slice<<<sgrid, 256, 0, stream>>>(TqA, nullptr, Tk(1), TqB, rowptr, ecv, 1.f, 0.f);
    // T2 = 2 L T1 - T0
    cheb_level_slice<<<sgrid, 256, 0, stream>>>(TqB, Tk(0), Tk(2), TqA, rowptr, ecv, 2.f, 1.f);
    // T3 = 2 L T2 - T1
    cheb_level_slice<<<sgrid, 256, 0, stream>>>(TqA, Tk(1), Tk(3), TqB, rowptr, ecv, 2.f, 1.f);
    // T4 = 2 L T3 - T2
    cheb_level_slice<<<sgrid, 256, 0, stream>>>(TqB, Tk(2), Tk(4), TqA, rowptr, ecv, 2.f, 1.f);
    // T5 = 2 L T4 - T3 fused with epilogue (T3 bf16, A-frags all bf16)
    cheb_l5_epi_slice<<<grid, 256, 0, stream>>>(TqA, Tall, Wfrag, rowptr, ecv, out);
  } else {
    // ---------- fallback: bf16 fused epilogue, 2 T buffers ----------
    char* p = (char*)d_ws;
    size_t off = 0;
    unsigned short* bufA = (unsigned short*)(p + off); off += tbytes;
    unsigned short* bufB = (unsigned short*)(p + off); off += tbytes;
    int*   cnt    = (int*)(p + off); off += small;
    int*   rowptr = (int*)(p + off); off += small;
    int*   cursor = (int*)(p + off); off += small;
    int*   ccol   = (int*)(p + off); off += alignup((size_t)NNZE * 4);
    float* cval   = (float*)(p + off); off += alignup((size_t)NNZE * 4);

    hipMemsetAsync(cnt, 0, (size_t)NND * 4, stream);
    hist_kernel<<<(NNZE + 255) / 256, 256, 0, stream>>>(rows, cnt, NNZE);
    scan_kernel<<<1, 1024, 0, stream>>>(cnt, rowptr, cursor, NND);
    fill2_kernel<<<(NNZE + 255) / 256, 256, 0, stream>>>(rows, cols, vals, cursor, ccol, cval, NNZE);

    cheb_k0_fused<<<grid, 256, 0, stream>>>(x, bufA, W, out);
    cheb_level_fused<<<grid, 256, 0, stream>>>(bufA, bufB, rowptr, ccol, cval, W, out, 1, 1.f, 0.f, 1);
    cheb_level_fused<<<grid, 256, 0, stream>>>(bufB, bufA, rowptr, ccol, cval, W, out, 2, 2.f, 1.f, 1);
    cheb_level_fused<<<grid, 256, 0, stream>>>(bufA, bufB, rowptr, ccol, cval, W, out, 3, 2.f, 1.f, 1);
    cheb_level_fused<<<grid, 256, 0, stream>>>(bufB, bufA, rowptr, ccol, cval, W, out, 4, 2.f, 1.f, 1);
    cheb_level_fused<<<grid, 256, 0, stream>>>(bufA, bufB, rowptr, ccol, cval, W, out, 5, 2.f, 1.f, 0);
  }
}

// Round 8
// 549.994 us; speedup vs baseline: 1.7134x; 1.7134x over previous
//
#include <hip/hip_runtime.h>
#include <hip/hip_bf16.h>

// Problem constants (cheb_conv): B=16, N=50000, FIN=32, FOUT=32, K=6, NNZ=800000
#define NND   50000
#define NBATCH 16
#define NFIN  32
#define NFOUT 32
#define NCHEB 6
#define NNZE  800000
#define DDIM  512   // NBATCH*NFIN

typedef __attribute__((ext_vector_type(8))) short    short8;
typedef __attribute__((ext_vector_type(8))) unsigned short u16x8;
typedef __attribute__((ext_vector_type(4))) float    f32x4;
typedef __attribute__((ext_vector_type(2))) float    f32x2;

__device__ __forceinline__ float b2f(unsigned short u) {
  union { unsigned u; float f; } v; v.u = ((unsigned)u) << 16; return v.f;
}
__device__ __forceinline__ unsigned short f2bf(float f) {
  union { float f; unsigned u; } v; v.f = f;
  unsigned r = v.u + 0x7fffu + ((v.u >> 16) & 1u);   // RNE
  return (unsigned short)(r >> 16);
}
// f32 -> OCP e4m3fn byte, software RNE
__device__ __forceinline__ unsigned f2fp8(float f) {
  unsigned s = (__float_as_uint(f) >> 24) & 0x80u;
  float af = fminf(fabsf(f), 448.0f);
  unsigned b;
  if (af < 0.015625f) {
    b = (unsigned)__float2int_rn(af * 512.0f);
  } else {
    unsigned u = __float_as_uint(af);
    u += 0x7FFFFu + ((u >> 20) & 1u);
    b = (((u >> 23) - 120u) << 3) | ((u >> 20) & 7u);
    if (b > 0x7Eu) b = 0x7Eu;
  }
  return s | b;
}

// ---------------- CSR build ----------------
__global__ void hist_kernel(const int* __restrict__ rows, int* __restrict__ cnt, int nnz) {
  int e = blockIdx.x * blockDim.x + threadIdx.x;
  if (e < nnz) atomicAdd(&cnt[rows[e]], 1);
}

__global__ __launch_bounds__(1024) void scanA_kernel(const int* __restrict__ cnt,
                                                     int* __restrict__ rowptr,
                                                     int* __restrict__ partials, int n) {
  __shared__ int lds[1024];
  int b = blockIdx.x, tid = threadIdx.x, i = b * 1024 + tid;
  int v = (i < n) ? cnt[i] : 0;
  lds[tid] = v;
  __syncthreads();
  int s = v;
  for (int off = 1; off < 1024; off <<= 1) {
    int t = (tid >= off) ? lds[tid - off] : 0;
    __syncthreads();
    s += t;
    lds[tid] = s;
    __syncthreads();
  }
  if (i < n) rowptr[i] = s - v;
  if (tid == 1023) partials[b] = s;
}

// merged: thread 0 = serial partial-scan; threads 64..831 = W -> MFMA B-frag pack
__global__ void scanB_wprep(int* __restrict__ partials, int nb,
                            const float* __restrict__ W, unsigned short* __restrict__ Wfrag) {
  int t = threadIdx.x;
  if (t == 0) {
    int run = 0;
    for (int b = 0; b < nb; ++b) { int x = partials[b]; partials[b] = run; run += x; }
  } else if (t >= 64 && t < 64 + 768) {
    int w = t - 64;
    int frag = w >> 6, lane = w & 63;
    int kk = frag >> 1, h = frag & 1;
    int fo = (lane & 15) + h * 16, kc = (lane >> 4) * 8;
    u16x8 b;
#pragma unroll
    for (int j = 0; j < 8; ++j)
      b[j] = f2bf(W[((size_t)(kc + j) * NCHEB + kk) * NFOUT + fo]);
    *(u16x8*)(Wfrag + (size_t)w * 8) = b;
  }
}

__global__ __launch_bounds__(1024) void scanC_kernel(const int* __restrict__ partials,
                                                     int* __restrict__ rowptr,
                                                     int* __restrict__ cursor, int n) {
  int i = blockIdx.x * 1024 + threadIdx.x;
  if (i < n) {
    int r = rowptr[i] + partials[blockIdx.x];
    rowptr[i] = r;
    cursor[i] = r;
  }
  if (i == n) rowptr[n] = NNZE;
}

// packed edges: ecv[p] = (col in low 32) | (val bits in high 32)
__global__ void fill_kernel(const int* __restrict__ rows, const int* __restrict__ cols,
                            const float* __restrict__ vals, int* __restrict__ cursor,
                            long* __restrict__ ecv, int nnz) {
  int e = blockIdx.x * blockDim.x + threadIdx.x;
  if (e < nnz) {
    int r = rows[e];
    int p = atomicAdd(&cursor[r], 1);
    ecv[p] = (long)((unsigned long long)__float_as_uint(vals[e]) << 32 | (unsigned)cols[e]);
  }
}

// ---------------- Level 0: transpose x -> T0 (bf16 A-frag order) + fp8 copy ----------------
// T layout per node: pos = lane*8+j <-> (b = lane&15, fi = (lane>>4)*8 + j)
__global__ __launch_bounds__(256) void cheb_k0_q(const float* __restrict__ x,
                                                 unsigned short* __restrict__ T0,
                                                 char* __restrict__ Tq0) {
  int wave = threadIdx.x >> 6, lane = threadIdx.x & 63;
  int n = blockIdx.x * 4 + wave;
  int kc = (lane >> 4) * 8;
  int b  = lane & 15;

  const float* xp = x + ((size_t)b * NND + n) * NFIN + kc;
  float4 xa = *(const float4*)xp;
  float4 xb = *(const float4*)(xp + 4);
  float tv[8] = {xa.x, xa.y, xa.z, xa.w, xb.x, xb.y, xb.z, xb.w};

  u16x8 tb;
#pragma unroll
  for (int j = 0; j < 8; ++j) tb[j] = f2bf(tv[j]);
  *(u16x8*)(T0 + (size_t)n * DDIM + lane * 8) = tb;

  unsigned lo = f2fp8(tv[0]) | (f2fp8(tv[1]) << 8) | (f2fp8(tv[2]) << 16) | (f2fp8(tv[3]) << 24);
  unsigned hi = f2fp8(tv[4]) | (f2fp8(tv[5]) << 8) | (f2fp8(tv[6]) << 16) | (f2fp8(tv[7]) << 24);
  int2 qq; qq.x = (int)lo; qq.y = (int)hi;
  *(int2*)(Tq0 + (size_t)n * 512 + lane * 8) = qq;
}

// ---------------- fp8 FMA of one gathered row ----------------
__device__ __forceinline__ void fma8(float v, int2 d, float acc[8]) {
  f32x2 f01 = __builtin_amdgcn_cvt_pk_f32_fp8(d.x, false);
  f32x2 f23 = __builtin_amdgcn_cvt_pk_f32_fp8(d.x, true);
  f32x2 f45 = __builtin_amdgcn_cvt_pk_f32_fp8(d.y, false);
  f32x2 f67 = __builtin_amdgcn_cvt_pk_f32_fp8(d.y, true);
  acc[0] = fmaf(v, f01.x, acc[0]);
  acc[1] = fmaf(v, f01.y, acc[1]);
  acc[2] = fmaf(v, f23.x, acc[2]);
  acc[3] = fmaf(v, f23.y, acc[3]);
  acc[4] = fmaf(v, f45.x, acc[4]);
  acc[5] = fmaf(v, f45.y, acc[5]);
  acc[6] = fmaf(v, f67.x, acc[6]);
  acc[7] = fmaf(v, f67.y, acc[7]);
}

// ---------------- fp8 gather core: 8-deep batches (R4-proven structure) ----------------
__device__ __forceinline__ void gather_q(const char* __restrict__ qbase,  // Tq + lane*8
                                         const long* __restrict__ ecv,
                                         int s, int e1, float acc[8]) {
  int e = s;
  for (; e + 8 <= e1; e += 8) {
    long m[8];
#pragma unroll
    for (int q = 0; q < 8; ++q) m[q] = __builtin_nontemporal_load(ecv + e + q);
    int2 d[8];
#pragma unroll
    for (int q = 0; q < 8; ++q) d[q] = *(const int2*)(qbase + (size_t)(unsigned)m[q] * 512);
#pragma unroll
    for (int q = 0; q < 8; ++q) fma8(__int_as_float((int)(m[q] >> 32)), d[q], acc);
  }
  if (e + 4 <= e1) {
    long m[4];
#pragma unroll
    for (int q = 0; q < 4; ++q) m[q] = __builtin_nontemporal_load(ecv + e + q);
    int2 d[4];
#pragma unroll
    for (int q = 0; q < 4; ++q) d[q] = *(const int2*)(qbase + (size_t)(unsigned)m[q] * 512);
#pragma unroll
    for (int q = 0; q < 4; ++q) fma8(__int_as_float((int)(m[q] >> 32)), d[q], acc);
    e += 4;
  }
  for (; e < e1; ++e) {
    long mm = __builtin_nontemporal_load(ecv + e);
    int2 dd = *(const int2*)(qbase + (size_t)(unsigned)mm * 512);
    fma8(__int_as_float((int)(mm >> 32)), dd, acc);
  }
}

// ---------------- Levels 1..4: T_k = alpha*spmm_q(Tq_{k-1}) - beta*T_{k-2}; write bf16 + fp8 ----
__global__ __launch_bounds__(256) void cheb_level_q(const char* __restrict__ Tqprev,
                                                    const unsigned short* __restrict__ Tpp,
                                                    unsigned short* __restrict__ Tdst,
                                                    char* __restrict__ Tqdst,
                                                    const int* __restrict__ rowptr,
                                                    const long* __restrict__ ecv,
                                                    float alpha, float beta) {
  int wave = threadIdx.x >> 6, lane = threadIdx.x & 63;
  int n = blockIdx.x * 4 + wave;
  int s = rowptr[n], e1 = rowptr[n + 1];
  size_t rowoff = (size_t)n * DDIM + lane * 8;

  u16x8 tp2 = {};                              // early independent load
  if (beta != 0.f) tp2 = *(const u16x8*)(Tpp + rowoff);

  float acc[8] = {0.f, 0.f, 0.f, 0.f, 0.f, 0.f, 0.f, 0.f};
  gather_q(Tqprev + (size_t)lane * 8, ecv, s, e1, acc);

  float tk[8];
  if (beta != 0.f) {
#pragma unroll
    for (int j = 0; j < 8; ++j) tk[j] = alpha * acc[j] - beta * b2f(tp2[j]);
  } else {
#pragma unroll
    for (int j = 0; j < 8; ++j) tk[j] = alpha * acc[j];
  }

  u16x8 tkb;
#pragma unroll
  for (int j = 0; j < 8; ++j) tkb[j] = f2bf(tk[j]);
  *(u16x8*)(Tdst + rowoff) = tkb;

  unsigned lo = f2fp8(tk[0]) | (f2fp8(tk[1]) << 8) | (f2fp8(tk[2]) << 16) | (f2fp8(tk[3]) << 24);
  unsigned hi = f2fp8(tk[4]) | (f2fp8(tk[5]) << 8) | (f2fp8(tk[6]) << 16) | (f2fp8(tk[7]) << 24);
  int2 qq; qq.x = (int)lo; qq.y = (int)hi;
  *(int2*)(Tqdst + (size_t)n * 512 + lane * 8) = qq;
}

// ---------------- Level 5 fused with epilogue (Tall loads hoisted before gather) ----------
__global__ __launch_bounds__(256) void cheb_level5_epi_q(const char* __restrict__ Tq4,
                                                         const unsigned short* __restrict__ Tall,
                                                         const unsigned short* __restrict__ Wfrag,
                                                         const int* __restrict__ rowptr,
                                                         const long* __restrict__ ecv,
                                                         float* __restrict__ out) {
  int wave = threadIdx.x >> 6, lane = threadIdx.x & 63;
  int n = blockIdx.x * 4 + wave;
  int s = rowptr[n], e1 = rowptr[n + 1];
  size_t rowoff = (size_t)n * DDIM + lane * 8;

  // Independent A-fragment streams: issue BEFORE the gather so they ride along
  // with the first gather batches (values identical to R4; order-only change).
  short8 a[5];
#pragma unroll
  for (int kk = 0; kk < 5; ++kk)
    a[kk] = *(const short8*)(Tall + (size_t)kk * NND * DDIM + rowoff);

  float acc[8] = {0.f, 0.f, 0.f, 0.f, 0.f, 0.f, 0.f, 0.f};
  gather_q(Tq4 + (size_t)lane * 8, ecv, s, e1, acc);

  u16x8 tp2 = __builtin_bit_cast(u16x8, a[3]);   // T3 doubles as T_{k-2}
  u16x8 t5b;
#pragma unroll
  for (int j = 0; j < 8; ++j) t5b[j] = f2bf(2.f * acc[j] - b2f(tp2[j]));

  int fo = lane & 15;
  f32x4 c0 = {0.f, 0.f, 0.f, 0.f}, c1 = {0.f, 0.f, 0.f, 0.f};
#pragma unroll
  for (int kk = 0; kk < 5; ++kk) {
    short8 B0 = *(const short8*)(Wfrag + ((size_t)(kk * 2 + 0) * 64 + lane) * 8);
    short8 B1 = *(const short8*)(Wfrag + ((size_t)(kk * 2 + 1) * 64 + lane) * 8);
    c0 = __builtin_amdgcn_mfma_f32_16x16x32_bf16(a[kk], B0, c0, 0, 0, 0);
    c1 = __builtin_amdgcn_mfma_f32_16x16x32_bf16(a[kk], B1, c1, 0, 0, 0);
  }
  {
    short8 a5 = __builtin_bit_cast(short8, t5b);
    short8 B0 = *(const short8*)(Wfrag + ((size_t)(5 * 2 + 0) * 64 + lane) * 8);
    short8 B1 = *(const short8*)(Wfrag + ((size_t)(5 * 2 + 1) * 64 + lane) * 8);
    c0 = __builtin_amdgcn_mfma_f32_16x16x32_bf16(a5, B0, c0, 0, 0, 0);
    c1 = __builtin_amdgcn_mfma_f32_16x16x32_bf16(a5, B1, c1, 0, 0, 0);
  }

  int br = (lane >> 4) * 4;
#pragma unroll
  for (int r = 0; r < 4; ++r) {
    size_t o = ((size_t)(br + r) * NND + n) * NFOUT + fo;
    out[o]      = c0[r];
    out[o + 16] = c1[r];
  }
}

// ================= Fallback (bf16 fused epilogue, 2-buffer ping-pong) =================
__device__ __forceinline__ void gather_row(const unsigned short* __restrict__ gbase,
                                           const int* __restrict__ ccol,
                                           const float* __restrict__ cval,
                                           int s, int e1, float acc[8]) {
  int e = s;
  for (; e + 4 <= e1; e += 4) {
    int c[4]; float v[4];
#pragma unroll
    for (int q = 0; q < 4; ++q) {
      c[q] = __builtin_nontemporal_load(ccol + e + q);
      v[q] = __builtin_nontemporal_load(cval + e + q);
    }
    u16x8 t[4];
#pragma unroll
    for (int q = 0; q < 4; ++q) t[q] = *(const u16x8*)(gbase + (size_t)c[q] * DDIM);
#pragma unroll
    for (int q = 0; q < 4; ++q)
#pragma unroll
      for (int j = 0; j < 8; ++j) acc[j] = fmaf(v[q], b2f(t[q][j]), acc[j]);
  }
  for (; e < e1; ++e) {
    int   ci = __builtin_nontemporal_load(ccol + e);
    float vi = __builtin_nontemporal_load(cval + e);
    u16x8 ti = *(const u16x8*)(gbase + (size_t)ci * DDIM);
#pragma unroll
    for (int j = 0; j < 8; ++j) acc[j] = fmaf(vi, b2f(ti[j]), acc[j]);
  }
}

__global__ void scan_kernel(const int* __restrict__ cnt, int* __restrict__ rowptr,
                            int* __restrict__ cursor, int n) {
  __shared__ int lds[1024];
  int tid = threadIdx.x;
  int run = 0;
  for (int base = 0; base <= n; base += 1024) {
    int i = base + tid;
    int v = (i < n) ? cnt[i] : 0;
    lds[tid] = v;
    __syncthreads();
    int s = v;
    for (int off = 1; off < 1024; off <<= 1) {
      int t = (tid >= off) ? lds[tid - off] : 0;
      __syncthreads();
      s += t;
      lds[tid] = s;
      __syncthreads();
    }
    int excl = run + s - v;
    if (i <= n) {
      rowptr[i] = excl;
      if (i < n) cursor[i] = excl;
    }
    run += lds[1023];
    __syncthreads();
  }
}

__global__ void fill2_kernel(const int* __restrict__ rows, const int* __restrict__ cols,
                             const float* __restrict__ vals, int* __restrict__ cursor,
                             int* __restrict__ ccol, float* __restrict__ cval, int nnz) {
  int e = blockIdx.x * blockDim.x + threadIdx.x;
  if (e < nnz) {
    int r = rows[e];
    int p = atomicAdd(&cursor[r], 1);
    ccol[p] = cols[e];
    cval[p] = vals[e];
  }
}

__global__ __launch_bounds__(256) void cheb_k0_fused(const float* __restrict__ x,
                                                     unsigned short* __restrict__ T0,
                                                     const float* __restrict__ W,
                                                     float* __restrict__ out) {
  int wave = threadIdx.x >> 6, lane = threadIdx.x & 63;
  int n = blockIdx.x * 4 + wave;
  int fo = lane & 15, kc = (lane >> 4) * 8;
  int b  = lane & 15;

  const float* xp = x + ((size_t)b * NND + n) * NFIN + kc;
  float4 xa = *(const float4*)xp;
  float4 xb = *(const float4*)(xp + 4);
  float tv[8] = {xa.x, xa.y, xa.z, xa.w, xb.x, xb.y, xb.z, xb.w};

  u16x8 tb;
#pragma unroll
  for (int j = 0; j < 8; ++j) tb[j] = f2bf(tv[j]);
  *(u16x8*)(T0 + (size_t)n * DDIM + lane * 8) = tb;

  short8 B0, B1;
#pragma unroll
  for (int j = 0; j < 8; ++j) {
    int fi = kc + j;
    const float* wp = W + ((size_t)fi * NCHEB + 0) * NFOUT + fo;
    B0[j] = (short)f2bf(wp[0]);
    B1[j] = (short)f2bf(wp[16]);
  }
  f32x4 c0 = {0.f, 0.f, 0.f, 0.f}, c1 = {0.f, 0.f, 0.f, 0.f};
  short8 a = __builtin_bit_cast(short8, tb);
  c0 = __builtin_amdgcn_mfma_f32_16x16x32_bf16(a, B0, c0, 0, 0, 0);
  c1 = __builtin_amdgcn_mfma_f32_16x16x32_bf16(a, B1, c1, 0, 0, 0);

  int br = (lane >> 4) * 4;
#pragma unroll
  for (int r = 0; r < 4; ++r) {
    size_t o = ((size_t)(br + r) * NND + n) * NFOUT + fo;
    out[o]      = c0[r];
    out[o + 16] = c1[r];
  }
}

__global__ __launch_bounds__(256) void cheb_level_fused(const unsigned short* __restrict__ Tprev,
                                                        unsigned short* __restrict__ Tio,
                                                        const int* __restrict__ rowptr,
                                                        const int* __restrict__ ccol,
                                                        const float* __restrict__ cval,
                                                        const float* __restrict__ W,
                                                        float* __restrict__ out,
                                                        int kk, float alpha, float beta, int writeT) {
  int wave = threadIdx.x >> 6, lane = threadIdx.x & 63;
  int n = blockIdx.x * 4 + wave;
  int fo = lane & 15, kc = (lane >> 4) * 8;

  short8 B0, B1;
#pragma unroll
  for (int j = 0; j < 8; ++j) {
    int fi = kc + j;
    const float* wp = W + ((size_t)fi * NCHEB + kk) * NFOUT + fo;
    B0[j] = (short)f2bf(wp[0]);
    B1[j] = (short)f2bf(wp[16]);
  }

  float acc[8] = {0.f, 0.f, 0.f, 0.f, 0.f, 0.f, 0.f, 0.f};
  int s = rowptr[n], e1 = rowptr[n + 1];
  gather_row(Tprev + lane * 8, ccol, cval, s, e1, acc);

  unsigned short* iop = Tio + (size_t)n * DDIM + lane * 8;
  float tk[8];
  if (beta != 0.f) {
    u16x8 tp2 = *(const u16x8*)iop;
#pragma unroll
    for (int j = 0; j < 8; ++j) tk[j] = alpha * acc[j] - beta * b2f(tp2[j]);
  } else {
#pragma unroll
    for (int j = 0; j < 8; ++j) tk[j] = alpha * acc[j];
  }

  u16x8 tkb;
#pragma unroll
  for (int j = 0; j < 8; ++j) tkb[j] = f2bf(tk[j]);
  if (writeT) *(u16x8*)iop = tkb;

  f32x4 c0 = {0.f, 0.f, 0.f, 0.f}, c1 = {0.f, 0.f, 0.f, 0.f};
  short8 a = __builtin_bit_cast(short8, tkb);
  c0 = __builtin_amdgcn_mfma_f32_16x16x32_bf16(a, B0, c0, 0, 0, 0);
  c1 = __builtin_amdgcn_mfma_f32_16x16x32_bf16(a, B1, c1, 0, 0, 0);

  int br = (lane >> 4) * 4;
#pragma unroll
  for (int r = 0; r < 4; ++r) {
    size_t o = ((size_t)(br + r) * NND + n) * NFOUT + fo;
    out[o]      += c0[r];
    out[o + 16] += c1[r];
  }
}

// ---------------- launch ----------------
static inline size_t alignup(size_t v) { return (v + 255) & ~(size_t)255; }

extern "C" void kernel_launch(void* const* d_in, const int* in_sizes, int n_in,
                              void* d_out, int out_size, void* d_ws, size_t ws_size,
                              hipStream_t stream) {
  const float* x    = (const float*)d_in[0];
  const int*   rows = (const int*)d_in[1];
  const int*   cols = (const int*)d_in[2];
  const float* vals = (const float*)d_in[3];
  const float* W    = (const float*)d_in[4];
  float* out = (float*)d_out;

  const size_t tbytes = alignup((size_t)NND * DDIM * 2);     // one bf16 T level (51.2 MB)
  const size_t qbytes = alignup((size_t)NND * 512);          // one fp8 T level (25.6 MB)
  const size_t small  = alignup((size_t)(NND + 1) * 4);
  const size_t need_q = 5 * tbytes + 2 * qbytes + alignup(12 * 64 * 8 * 2)
                      + 4 * small + alignup((size_t)NNZE * 8);

  const int grid  = NND / 4;                 // 12500 blocks x 256 threads, one wave/node
  const int nscan = (NND + 1023) / 1024;     // 49

  if (ws_size >= need_q) {
    // ---------- fp8-gather deferred path (R4-proven) ----------
    char* p = (char*)d_ws;
    size_t off = 0;
    unsigned short* Tall  = (unsigned short*)(p + off); off += 5 * tbytes;   // T0..T4 bf16
    char* bufQA = (char*)(p + off); off += qbytes;
    char* bufQB = (char*)(p + off); off += qbytes;
    unsigned short* Wfrag = (unsigned short*)(p + off); off += alignup(12 * 64 * 8 * 2);
    int*  cnt      = (int*)(p + off); off += small;
    int*  rowptr   = (int*)(p + off); off += small;
    int*  cursor   = (int*)(p + off); off += small;
    int*  partials = (int*)(p + off); off += small;
    long* ecv      = (long*)(p + off); off += alignup((size_t)NNZE * 8);

    hipMemsetAsync(cnt, 0, (size_t)NND * 4, stream);
    hist_kernel<<<(NNZE + 255) / 256, 256, 0, stream>>>(rows, cnt, NNZE);
    scanA_kernel<<<nscan, 1024, 0, stream>>>(cnt, rowptr, partials, NND);
    scanB_wprep<<<1, 832, 0, stream>>>(partials, nscan, W, Wfrag);
    scanC_kernel<<<nscan, 1024, 0, stream>>>(partials, rowptr, cursor, NND);
    fill_kernel<<<(NNZE + 255) / 256, 256, 0, stream>>>(rows, cols, vals, cursor, ecv, NNZE);

    auto Tk = [&](int k) { return Tall + (size_t)k * NND * DDIM; };

    cheb_k0_q<<<grid, 256, 0, stream>>>(x, Tk(0), bufQA);
    cheb_level_q<<<grid, 256, 0, stream>>>(bufQA, nullptr, Tk(1), bufQB, rowptr, ecv, 1.f, 0.f);
    cheb_level_q<<<grid, 256, 0, stream>>>(bufQB, Tk(0), Tk(2), bufQA, rowptr, ecv, 2.f, 1.f);
    cheb_level_q<<<grid, 256, 0, stream>>>(bufQA, Tk(1), Tk(3), bufQB, rowptr, ecv, 2.f, 1.f);
    cheb_level_q<<<grid, 256, 0, stream>>>(bufQB, Tk(2), Tk(4), bufQA, rowptr, ecv, 2.f, 1.f);
    cheb_level5_epi_q<<<grid, 256, 0, stream>>>(bufQA, Tall, Wfrag, rowptr, ecv, out);
  } else {
    // ---------- fallback: bf16 fused epilogue, 2 T buffers ----------
    char* p = (char*)d_ws;
    size_t off = 0;
    unsigned short* bufA = (unsigned short*)(p + off); off += tbytes;
    unsigned short* bufB = (unsigned short*)(p + off); off += tbytes;
    int*   cnt    = (int*)(p + off); off += small;
    int*   rowptr = (int*)(p + off); off += small;
    int*   cursor = (int*)(p + off); off += small;
    int*   ccol   = (int*)(p + off); off += alignup((size_t)NNZE * 4);
    float* cval   = (float*)(p + off); off += alignup((size_t)NNZE * 4);

    hipMemsetAsync(cnt, 0, (size_t)NND * 4, stream);
    hist_kernel<<<(NNZE + 255) / 256, 256, 0, stream>>>(rows, cnt, NNZE);
    scan_kernel<<<1, 1024, 0, stream>>>(cnt, rowptr, cursor, NND);
    fill2_kernel<<<(NNZE + 255) / 256, 256, 0, stream>>>(rows, cols, vals, cursor, ccol, cval, NNZE);

    cheb_k0_fused<<<grid, 256, 0, stream>>>(x, bufA, W, out);
    cheb_level_fused<<<grid, 256, 0, stream>>>(bufA, bufB, rowptr, ccol, cval, W, out, 1, 1.f, 0.f, 1);
    cheb_level_fused<<<grid, 256, 0, stream>>>(bufB, bufA, rowptr, ccol, cval, W, out, 2, 2.f, 1.f, 1);
    cheb_level_fused<<<grid, 256, 0, stream>>>(bufA, bufB, rowptr, ccol, cval, W, out, 3, 2.f, 1.f, 1);
    cheb_level_fused<<<grid, 256, 0, stream>>>(bufB, bufA, rowptr, ccol, cval, W, out, 4, 2.f, 1.f, 1);
    cheb_level_fused<<<grid, 256, 0, stream>>>(bufA, bufB, rowptr, ccol, cval, W, out, 5, 2.f, 1.f, 0);
  }
}